// Round 8
// baseline (45.664 us; speedup 1.0000x reference)
//
#include <hip/hip_runtime.h>
#include <hip/hip_bf16.h>

// ContrastiveLoss fused kernel for MI355X (gfx950).
//
// Math reduction (T=0.5):
//   f = x / max(||x||, 1e-8)   (rows)
//   s_ij = f_i . f_j
//   den_i = sum_{j: label_j != label_i} exp(2 s_ij)
//   loss  = sum_i [ c_i * log(den_i) - sum_{j same label, j != i} 2 s_ij ]
//           / (sum_i c_i + 1e-5),   c_i = count(label_i) - 1
//
// N=4096, D=512, labels in [0,100).
//
// Round 8: SYMMETRY HALVING. s_ij = s_ji and den/pos contributions are
// symmetric, so decompose into 128x128 tile PAIRS (ti<=tj): 528 blocks
// instead of 1024. Off-diagonal blocks accumulate each computed e/s2
// twice: row-path (den/pos[i in ti], as before) and col-path
// (den/pos[j in tj]: kg-shuffle reduce + LDS colden/colpos, one global
// atomic per col at block end). Diagonal blocks: row-path only (covers
// both orders). Pipeline structure = proven round-5 kernel (A 2x16
// pinned, 32-row dbuf slabs, fragment-major global+LDS, conflict-free).

typedef short short8 __attribute__((ext_vector_type(8)));
typedef float floatx4 __attribute__((ext_vector_type(4)));
typedef unsigned short u16;
typedef unsigned int u32;
typedef unsigned char u8;

#define N_ROWS 4096
#define DIM 512
#define GRPB 16384             // bytes per 16-row fragment group (16*1024)
#define EPS_NORM 1e-8f
#define EPS_DEN 1e-5f
#define TI 128                 // tile size (rows and cols)
#define NT (N_ROWS / TI)       // 32 tiles
#define NPAIR (NT * (NT + 1) / 2)   // 528 blocks
#define NJT (TI / 32)          // 4 slabs of 32 j-rows

static __device__ inline u16 f32_to_bf16(float f) {
  u32 u = __float_as_uint(f);
  u32 r = (u + 0x7FFFu + ((u >> 16) & 1u)) >> 16;   // RNE
  return (u16)r;
}

static __device__ inline void load_lds16(const char* g, char* l) {
  __builtin_amdgcn_global_load_lds(
      (const __attribute__((address_space(1))) void*)g,
      (__attribute__((address_space(3))) void*)l, 16, 0, 0);
}

// wave-per-row normalize + bf16 pack, fragment-major store; grid 1024 x 256.
// G layout: group g = row>>4 (16 rows), chunk kt = k>>5 (32 elems), inside a
// 1 KB chunk lane l = kg*16 + (row&15) holds bytes [l*16, l*16+16) =
// elems k = kt*32 + kg*8 .. +8 of its row (the MFMA A/B fragment map).
__global__ void k1_normalize(const float* __restrict__ x,
                             const int* __restrict__ labels,
                             u16* __restrict__ G, u8* __restrict__ lab8,
                             float* __restrict__ den, float* __restrict__ pos,
                             float* __restrict__ acc2) {
  const int row = blockIdx.x * 4 + (threadIdx.x >> 6);
  const int lane = threadIdx.x & 63;
  const float4* src = reinterpret_cast<const float4*>(x + (size_t)row * DIM);
  float4 v0 = src[lane * 2];
  float4 v1 = src[lane * 2 + 1];
  float ss = v0.x*v0.x + v0.y*v0.y + v0.z*v0.z + v0.w*v0.w
           + v1.x*v1.x + v1.y*v1.y + v1.z*v1.z + v1.w*v1.w;
#pragma unroll
  for (int m = 1; m < 64; m <<= 1) ss += __shfl_xor(ss, m, 64);
  float scale = 1.f / fmaxf(sqrtf(ss), EPS_NORM);
  uint4 o;
  o.x = ((u32)f32_to_bf16(v0.y * scale) << 16) | (u32)f32_to_bf16(v0.x * scale);
  o.y = ((u32)f32_to_bf16(v0.w * scale) << 16) | (u32)f32_to_bf16(v0.z * scale);
  o.z = ((u32)f32_to_bf16(v1.y * scale) << 16) | (u32)f32_to_bf16(v1.x * scale);
  o.w = ((u32)f32_to_bf16(v1.w * scale) << 16) | (u32)f32_to_bf16(v1.z * scale);
  char* dst = (char*)G + (size_t)(row >> 4) * GRPB + (lane >> 2) * 1024
            + ((lane & 3) * 16 + (row & 15)) * 16;
  *reinterpret_cast<uint4*>(dst) = o;
  if (lane == 0) { den[row] = 0.f; pos[row] = 0.f; }
  if (lane == 1) lab8[row] = (u8)labels[row];
  if (blockIdx.x == 0 && threadIdx.x == 0) { acc2[0] = 0.f; acc2[1] = 0.f; }
}

// fused sim-GEMM + symmetric per-row/per-col reduction.
__global__ __launch_bounds__(256, 2) void k2_fused(
    const u16* __restrict__ G, const u8* __restrict__ lab8,
    float* __restrict__ den, float* __restrict__ pos) {
  // fragment-major B: 2 buffers x 32 chunks (js*16+kt) x 1 KB
  __shared__ u16 Bsh[2 * 32 * 512];
  __shared__ int labj_sh[TI];
  __shared__ float colden[TI], colpos[TI];

  const char* Gb = (const char*)G;
  char* bshb = (char*)Bsh;

  // decode pair (ti, tj), ti <= tj, from blockIdx
  int b = blockIdx.x;
  int ti = 0, rem = NT;
  while (b >= rem) { b -= rem; ++ti; --rem; }
  const int tj = ti + b;
  const bool diag = (ti == tj);

  const int tid = threadIdx.x;
  const int wv = tid >> 6;
  const int lane = tid & 63;
  const int l15 = lane & 15;
  const int kg = lane >> 4;               // 0..3

  const int ib = ti * TI;
  const int jb = tj * TI;

  // stage one 32-row B slab (2 fragment groups) as 32 chunks; wave wv stages
  // chunks wv*8 .. wv*8+7. Source AND dest contiguous 1 KB (lane*16).
#define STAGE(bufsel, grow) do {                                            \
    _Pragma("unroll")                                                       \
    for (int i_ = 0; i_ < 8; ++i_) {                                        \
      const int c_ = wv * 8 + i_;                                           \
      load_lds16(Gb + (size_t)(((grow) >> 4) + (c_ >> 4)) * GRPB            \
                    + (c_ & 15) * 1024 + lane * 16,                         \
                 bshb + (bufsel) * 32768 + c_ * 1024 + lane * 16);          \
    }                                                                       \
  } while (0)

  // prologue: stage slab 0 into buf 0, labels + col accumulators into LDS
  STAGE(0, jb);
  if (tid < TI) {
    labj_sh[tid] = lab8[jb + tid];
    colden[tid] = 0.f;
    colpos[tid] = 0.f;
  }

  // A fragments: 32 rows/wave = 2 fragment groups, K=512, register-resident.
  short8 a[2][16];
#pragma unroll
  for (int s = 0; s < 2; ++s) {
    const char* abase = Gb + (size_t)(ti * 8 + wv * 2 + s) * GRPB + lane * 16;
#pragma unroll
    for (int kt = 0; kt < 16; ++kt)
      a[s][kt] = *reinterpret_cast<const short8*>(abase + kt * 1024);
  }
  // pin A in VGPRs (round-1 pathology: compiler sank loads into the loop)
#pragma unroll
  for (int s = 0; s < 2; ++s)
#pragma unroll
    for (int kt = 0; kt < 16; ++kt)
      asm volatile("" : "+v"(a[s][kt]));

  // C/D layout (verified gfx950): col = lane&15 (j), row = kg*4 + r (i).
  // lane's 8 output rows: i = i_base + s*16 + r; labels packed u8x4.
  const int i_base = ib + wv * 32 + kg * 4;
  const u32 labp0 = *reinterpret_cast<const u32*>(lab8 + i_base);
  const u32 labp1 = *reinterpret_cast<const u32*>(lab8 + i_base + 16);

  float den_acc[2][4] = {{0.f,0.f,0.f,0.f},{0.f,0.f,0.f,0.f}};
  float pos_acc[2][4] = {{0.f,0.f,0.f,0.f},{0.f,0.f,0.f,0.f}};

  __syncthreads();   // buf0 staged, labels + col accs ready

  for (int jt = 0; jt < NJT; ++jt) {
    const int cur = jt & 1;
    if (jt + 1 < NJT) STAGE(cur ^ 1, jb + (jt + 1) * 32);

    const int j0 = jt * 32;
    const int jrow0 = jb + j0 + l15;           // js = 0
    const int jrow1 = jrow0 + 16;              // js = 1
    const int labj0 = labj_sh[j0 + l15];
    const int labj1 = labj_sh[j0 + 16 + l15];

    // 4 independent MFMA chains: (i-set 0/1) x (j-subtile 0/1).
    floatx4 acc00 = {0.f,0.f,0.f,0.f}, acc01 = {0.f,0.f,0.f,0.f};
    floatx4 acc10 = {0.f,0.f,0.f,0.f}, acc11 = {0.f,0.f,0.f,0.f};
    const char* bbase = bshb + cur * 32768 + lane * 16;
#pragma unroll
    for (int kt = 0; kt < 16; ++kt) {
      short8 b0 = *reinterpret_cast<const short8*>(bbase + kt * 1024);
      short8 b1 = *reinterpret_cast<const short8*>(bbase + 16384 + kt * 1024);
      acc00 = __builtin_amdgcn_mfma_f32_16x16x32_bf16(a[0][kt], b0, acc00, 0, 0, 0);
      acc10 = __builtin_amdgcn_mfma_f32_16x16x32_bf16(a[1][kt], b0, acc10, 0, 0, 0);
      acc01 = __builtin_amdgcn_mfma_f32_16x16x32_bf16(a[0][kt], b1, acc01, 0, 0, 0);
      acc11 = __builtin_amdgcn_mfma_f32_16x16x32_bf16(a[1][kt], b1, acc11, 0, 0, 0);
    }

    float cd0 = 0.f, cp0 = 0.f, cd1 = 0.f, cp1 = 0.f;  // col partials (js 0/1)
#pragma unroll
    for (int s = 0; s < 2; ++s) {
      floatx4 aj0 = s ? acc10 : acc00;
      floatx4 aj1 = s ? acc11 : acc01;
      const u32 labp = s ? labp1 : labp0;
#pragma unroll
      for (int r = 0; r < 4; ++r) {
        const int labi = (int)((labp >> (8 * r)) & 255u);
        const int irow = i_base + s * 16 + r;
        float s20 = 2.f * aj0[r];
        float s21 = 2.f * aj1[r];
        float e0 = __expf(s20);
        float e1 = __expf(s21);
        bool sm0 = (labj0 == labi);
        bool sm1 = (labj1 == labi);
        float d0 = sm0 ? 0.f : e0;
        float d1 = sm1 ? 0.f : e1;
        float p0 = (sm0 && (jrow0 != irow)) ? s20 : 0.f;
        float p1 = (sm1 && (jrow1 != irow)) ? s21 : 0.f;
        den_acc[s][r] += d0 + d1;
        pos_acc[s][r] += p0 + p1;
        cd0 += d0; cp0 += p0;
        cd1 += d1; cp1 += p1;
      }
    }
    if (!diag) {
      // reduce col partials across the 4 kg groups (lanes sharing l15)
      cd0 += __shfl_xor(cd0, 16, 64); cd0 += __shfl_xor(cd0, 32, 64);
      cp0 += __shfl_xor(cp0, 16, 64); cp0 += __shfl_xor(cp0, 32, 64);
      cd1 += __shfl_xor(cd1, 16, 64); cd1 += __shfl_xor(cd1, 32, 64);
      cp1 += __shfl_xor(cp1, 16, 64); cp1 += __shfl_xor(cp1, 32, 64);
      if (kg == 0) {
        atomicAdd(&colden[j0 + l15], cd0);
        atomicAdd(&colpos[j0 + l15], cp0);
        atomicAdd(&colden[j0 + 16 + l15], cd1);
        atomicAdd(&colpos[j0 + 16 + l15], cp1);
      }
    }
    __syncthreads();   // staging for jt+1 done; safe to flip buffers
  }

  // row path: reduce across the 16 cols (lanes with same kg), 1 atomic/row
#pragma unroll
  for (int s = 0; s < 2; ++s)
#pragma unroll
    for (int r = 0; r < 4; ++r) {
      float dd = den_acc[s][r], p = pos_acc[s][r];
#pragma unroll
      for (int m = 1; m < 16; m <<= 1) {
        dd += __shfl_xor(dd, m, 64);
        p += __shfl_xor(p, m, 64);
      }
      if (l15 == 0) {
        atomicAdd(&den[i_base + s * 16 + r], dd);
        atomicAdd(&pos[i_base + s * 16 + r], p);
      }
    }

  // col path flush (off-diagonal blocks): one atomic per col
  if (!diag) {
    __syncthreads();   // all waves' LDS col atomics done
    if (tid < TI) {
      atomicAdd(&den[jb + tid], colden[tid]);
      atomicAdd(&pos[jb + tid], colpos[tid]);
    }
  }
#undef STAGE
}

// per-row finalize, 16 blocks x 256 threads; block partial -> global atomics
__global__ void k3a(const float* __restrict__ den, const float* __restrict__ pos,
                    const int* __restrict__ labels, float* __restrict__ acc2) {
  __shared__ int hist[128];
  __shared__ float sn[4], sz[4];
  const int tid = threadIdx.x;
  if (tid < 128) hist[tid] = 0;
  __syncthreads();
  for (int i = tid; i < N_ROWS; i += 256) atomicAdd(&hist[labels[i]], 1);
  __syncthreads();

  const int row = blockIdx.x * 256 + tid;
  int c = hist[labels[row]] - 1;
  float num = (float)c * logf(den[row]) - pos[row];
  float nnz = (float)c;
#pragma unroll
  for (int m = 1; m < 64; m <<= 1) {
    num += __shfl_xor(num, m, 64);
    nnz += __shfl_xor(nnz, m, 64);
  }
  if ((tid & 63) == 0) { sn[tid >> 6] = num; sz[tid >> 6] = nnz; }
  __syncthreads();
  if (tid == 0) {
    atomicAdd(&acc2[0], sn[0] + sn[1] + sn[2] + sn[3]);
    atomicAdd(&acc2[1], sz[0] + sz[1] + sz[2] + sz[3]);
  }
}

__global__ void k3b(const float* __restrict__ acc2, float* __restrict__ out) {
  out[0] = acc2[0] / (acc2[1] + EPS_DEN);
}

extern "C" void kernel_launch(void* const* d_in, const int* in_sizes, int n_in,
                              void* d_out, int out_size, void* d_ws, size_t ws_size,
                              hipStream_t stream) {
  const float* x = (const float*)d_in[0];
  const int* labels = (const int*)d_in[1];

  // ws: G (4MB) | den f32[4096] | pos f32[4096] | lab8 u8[4096] | acc2 f32[2]
  u16* G = (u16*)d_ws;
  float* den = (float*)((char*)d_ws + (size_t)N_ROWS * DIM * 2);
  float* pos = den + N_ROWS;
  u8* lab8 = (u8*)(pos + N_ROWS);
  float* acc2 = (float*)(lab8 + N_ROWS);
  float* out = (float*)d_out;

  hipLaunchKernelGGL(k1_normalize, dim3(N_ROWS / 4), dim3(256), 0, stream,
                     x, labels, G, lab8, den, pos, acc2);
  hipLaunchKernelGGL(k2_fused, dim3(NPAIR), dim3(256), 0, stream,
                     G, lab8, den, pos);
  hipLaunchKernelGGL(k3a, dim3(16), dim3(256), 0, stream,
                     den, pos, labels, acc2);
  hipLaunchKernelGGL(k3b, dim3(1), dim3(1), 0, stream, acc2, out);
}